// Round 1
// baseline (405.050 us; speedup 1.0000x reference)
//
#include <hip/hip_runtime.h>

#define NNODES 40000
#define NEDGES 640000
// IN_F = 128, HID = 128, OUT_F = 64

// ---------------- edge dtype detection (int64 vs int32) ----------------
// Node ids < 40000 < 2^31, so for an int64 buffer every odd 32-bit word is 0.
// For an int32 buffer the odd words are random node ids (P(all 64 == 0) ~ 0).
__global__ void detect64_kernel(const int* __restrict__ e32, int* __restrict__ flag) {
    if (blockIdx.x == 0 && threadIdx.x == 0) {
        int any = 0;
        for (int i = 0; i < 64; ++i) any |= e32[2 * i + 1];
        *flag = (any == 0) ? 1 : 0;
    }
}

static __device__ __forceinline__ int edge_val(const void* ep, long long idx, int is64) {
    if (is64) return (int)((const long long*)ep)[idx];
    return ((const int*)ep)[idx];
}

// ---------------- CSR build ----------------
__global__ void hist_kernel(const void* __restrict__ edges, const int* __restrict__ flag,
                            int* __restrict__ cnt) {
    int e = blockIdx.x * 256 + threadIdx.x;
    if (e >= NEDGES) return;
    int is64 = *flag;
    int d = edge_val(edges, (long long)NEDGES + e, is64);
    atomicAdd(&cnt[d], 1);
}

__global__ void scan_part_kernel(const int* __restrict__ cnt, int* __restrict__ excl,
                                 int* __restrict__ bsums, int n) {
    __shared__ int s[256];
    int tid = threadIdx.x;
    int i = blockIdx.x * 256 + tid;
    int v = (i < n) ? cnt[i] : 0;
    s[tid] = v;
    __syncthreads();
    for (int off = 1; off < 256; off <<= 1) {
        int t = (tid >= off) ? s[tid - off] : 0;
        __syncthreads();
        s[tid] += t;
        __syncthreads();
    }
    if (i < n) excl[i] = s[tid] - v;
    if (tid == 255) bsums[blockIdx.x] = s[255];
}

__global__ void scan_top_kernel(const int* __restrict__ bsums, int* __restrict__ boffs, int nb) {
    __shared__ int s[256];
    int tid = threadIdx.x;
    int v = (tid < nb) ? bsums[tid] : 0;
    s[tid] = v;
    __syncthreads();
    for (int off = 1; off < 256; off <<= 1) {
        int t = (tid >= off) ? s[tid - off] : 0;
        __syncthreads();
        s[tid] += t;
        __syncthreads();
    }
    if (tid < nb) boffs[tid] = s[tid] - v;
}

__global__ void addback_kernel(const int* __restrict__ excl, const int* __restrict__ boffs,
                               const int* __restrict__ cnt, int* __restrict__ row_start,
                               int* __restrict__ cursor, float* __restrict__ inv_cnt, int n) {
    int i = blockIdx.x * 256 + threadIdx.x;
    if (i >= n) return;
    int st = excl[i] + boffs[blockIdx.x];
    row_start[i] = st;
    cursor[i] = st;
    int c = cnt[i];
    inv_cnt[i] = 1.0f / (float)(c > 0 ? c : 1);
}

__global__ void fill_kernel(const void* __restrict__ edges, const int* __restrict__ flag,
                            int* __restrict__ cursor, int* __restrict__ csr_src) {
    int e = blockIdx.x * 256 + threadIdx.x;
    if (e >= NEDGES) return;
    int is64 = *flag;
    int s = edge_val(edges, e, is64);
    int d = edge_val(edges, (long long)NEDGES + e, is64);
    int p = atomicAdd(&cursor[d], 1);
    csr_src[p] = s;
}

// ---------------- weight packing: Wc = [Wl | Wr] ----------------
__global__ void pack1_kernel(const float* __restrict__ W1l, const float* __restrict__ W1r,
                             float* __restrict__ Wc1) {
    int i = blockIdx.x * 256 + threadIdx.x;  // 128*256
    int k = i >> 8, j = i & 255;
    Wc1[i] = (j < 128) ? W1l[k * 128 + j] : W1r[k * 128 + (j - 128)];
}

__global__ void pack2_kernel(const float* __restrict__ W2l, const float* __restrict__ W2r,
                             float* __restrict__ Wc2) {
    int i = blockIdx.x * 256 + threadIdx.x;  // 128*128
    int k = i >> 7, j = i & 127;
    Wc2[i] = (j < 64) ? W2l[k * 64 + j] : W2r[k * 64 + (j - 64)];
}

// ---------------- GEMM: C[nrows][CO] = A[nrows][128] @ W[128][CO] ----------------
// block tile 128 rows x 128 cols, 256 threads, 8x8 per-thread register tile
__global__ __launch_bounds__(256) void gemm128_kernel(const float* __restrict__ A,
                                                      const float* __restrict__ W,
                                                      float* __restrict__ C, int nrows, int CO) {
    __shared__ float xs[16][132];  // [k][row] transposed A tile
    __shared__ float wt[16][132];  // [k][col] W tile
    int tid = threadIdx.x;
    int tx = tid & 15, ty = tid >> 4;
    int r0 = ty * 8, j0 = tx * 8;
    int row_base = blockIdx.x * 128;
    int col_base = blockIdx.y * 128;
    float acc[8][8];
#pragma unroll
    for (int i = 0; i < 8; ++i)
#pragma unroll
        for (int j = 0; j < 8; ++j) acc[i][j] = 0.f;

    for (int kc = 0; kc < 128; kc += 16) {
#pragma unroll
        for (int l = 0; l < 2; ++l) {
            int f4 = tid + l * 256;   // 0..511
            int r = f4 >> 2;          // 0..127
            int k4 = (f4 & 3) << 2;   // 0,4,8,12
            int row = row_base + r;
            float4 v = make_float4(0.f, 0.f, 0.f, 0.f);
            if (row < nrows) v = *(const float4*)&A[(size_t)row * 128 + kc + k4];
            xs[k4 + 0][r] = v.x;
            xs[k4 + 1][r] = v.y;
            xs[k4 + 2][r] = v.z;
            xs[k4 + 3][r] = v.w;
        }
#pragma unroll
        for (int l = 0; l < 2; ++l) {
            int f4 = tid + l * 256;
            int k = f4 >> 5;           // 0..15
            int j4 = (f4 & 31) << 2;   // 0..124
            *(float4*)&wt[k][j4] = *(const float4*)&W[(size_t)(kc + k) * CO + col_base + j4];
        }
        __syncthreads();
#pragma unroll
        for (int k = 0; k < 16; ++k) {
            float a[8], b[8];
            *(float4*)&a[0] = *(const float4*)&xs[k][r0];
            *(float4*)&a[4] = *(const float4*)&xs[k][r0 + 4];
            *(float4*)&b[0] = *(const float4*)&wt[k][j0];
            *(float4*)&b[4] = *(const float4*)&wt[k][j0 + 4];
#pragma unroll
            for (int i = 0; i < 8; ++i)
#pragma unroll
                for (int j = 0; j < 8; ++j) acc[i][j] = fmaf(a[i], b[j], acc[i][j]);
        }
        __syncthreads();
    }
#pragma unroll
    for (int i = 0; i < 8; ++i) {
        int row = row_base + r0 + i;
        if (row < nrows) {
            float4 v0 = make_float4(acc[i][0], acc[i][1], acc[i][2], acc[i][3]);
            float4 v1 = make_float4(acc[i][4], acc[i][5], acc[i][6], acc[i][7]);
            *(float4*)&C[(size_t)row * CO + col_base + j0] = v0;
            *(float4*)&C[(size_t)row * CO + col_base + j0 + 4] = v1;
        }
    }
}

// ---------------- layer-1 aggregation + bias + self term + relu ----------------
// T1: [N][256], cols 0..127 = x@W1l, cols 128..255 = x@W1r. h = relu(agg + b1 + xr)
__global__ __launch_bounds__(256) void agg1_kernel(const float* __restrict__ T1,
                                                   const int* __restrict__ row_start,
                                                   const int* __restrict__ cnt,
                                                   const float* __restrict__ inv_cnt,
                                                   const int* __restrict__ csr_src,
                                                   const float* __restrict__ b1,
                                                   float* __restrict__ h) {
    int t = blockIdx.x * 256 + threadIdx.x;
    int node = t >> 7;
    int f = t & 127;
    if (node >= NNODES) return;
    int beg = row_start[node];
    int c = cnt[node];
    float s = 0.f;
    for (int e = 0; e < c; ++e) {
        int src = csr_src[beg + e];
        s += T1[(size_t)src * 256 + f];
    }
    float v = s * inv_cnt[node] + b1[f] + T1[(size_t)node * 256 + 128 + f];
    h[(size_t)node * 128 + f] = fmaxf(v, 0.f);
}

// ---------------- layer-2 aggregation + bias + self term ----------------
// T2: [N][128], cols 0..63 = h@W2l, cols 64..127 = h@W2r. out = agg + b2 + hr
__global__ __launch_bounds__(256) void agg2_kernel(const float* __restrict__ T2,
                                                   const int* __restrict__ row_start,
                                                   const int* __restrict__ cnt,
                                                   const float* __restrict__ inv_cnt,
                                                   const int* __restrict__ csr_src,
                                                   const float* __restrict__ b2,
                                                   float* __restrict__ out) {
    int t = blockIdx.x * 256 + threadIdx.x;
    int node = t >> 6;
    int f = t & 63;
    if (node >= NNODES) return;
    int beg = row_start[node];
    int c = cnt[node];
    float s = 0.f;
    for (int e = 0; e < c; ++e) {
        int src = csr_src[beg + e];
        s += T2[(size_t)src * 128 + f];
    }
    out[(size_t)node * 64 + f] = s * inv_cnt[node] + b2[f] + T2[(size_t)node * 128 + 64 + f];
}

extern "C" void kernel_launch(void* const* d_in, const int* in_sizes, int n_in,
                              void* d_out, int out_size, void* d_ws, size_t ws_size,
                              hipStream_t stream) {
    const float* x   = (const float*)d_in[0];
    const void*  ei  = d_in[1];
    const float* W1l = (const float*)d_in[2];
    const float* b1  = (const float*)d_in[3];
    const float* W1r = (const float*)d_in[4];
    const float* W2l = (const float*)d_in[5];
    const float* b2  = (const float*)d_in[6];
    const float* W2r = (const float*)d_in[7];
    float* out = (float*)d_out;

    char* p = (char*)d_ws;
    auto alloc = [&](size_t bytes) {
        char* r = p;
        p += (bytes + 255) & ~(size_t)255;
        return r;
    };
    int*   flag      = (int*)alloc(4);
    int*   cnt       = (int*)alloc(NNODES * 4);
    int*   excl      = (int*)alloc(NNODES * 4);
    int*   bsums     = (int*)alloc(256 * 4);
    int*   boffs     = (int*)alloc(256 * 4);
    int*   row_start = (int*)alloc(NNODES * 4);
    int*   cursor    = (int*)alloc(NNODES * 4);
    float* inv_cnt   = (float*)alloc(NNODES * 4);
    int*   csr_src   = (int*)alloc((size_t)NEDGES * 4);
    float* Wc1       = (float*)alloc(128 * 256 * 4);
    float* Wc2       = (float*)alloc(128 * 128 * 4);
    float* T1        = (float*)alloc((size_t)NNODES * 256 * 4);
    float* h         = (float*)alloc((size_t)NNODES * 128 * 4);
    float* T2        = (float*)alloc((size_t)NNODES * 128 * 4);

    const int nb = (NNODES + 255) / 256;  // 157

    hipMemsetAsync(cnt, 0, NNODES * 4, stream);
    detect64_kernel<<<1, 64, 0, stream>>>((const int*)ei, flag);
    pack1_kernel<<<(128 * 256) / 256, 256, 0, stream>>>(W1l, W1r, Wc1);
    pack2_kernel<<<(128 * 128) / 256, 256, 0, stream>>>(W2l, W2r, Wc2);
    hist_kernel<<<(NEDGES + 255) / 256, 256, 0, stream>>>(ei, flag, cnt);
    scan_part_kernel<<<nb, 256, 0, stream>>>(cnt, excl, bsums, NNODES);
    scan_top_kernel<<<1, 256, 0, stream>>>(bsums, boffs, nb);
    addback_kernel<<<nb, 256, 0, stream>>>(excl, boffs, cnt, row_start, cursor, inv_cnt, NNODES);
    fill_kernel<<<(NEDGES + 255) / 256, 256, 0, stream>>>(ei, flag, cursor, csr_src);

    // layer 1: T1 = x @ [W1l | W1r]
    gemm128_kernel<<<dim3((NNODES + 127) / 128, 2), 256, 0, stream>>>(x, Wc1, T1, NNODES, 256);
    agg1_kernel<<<(NNODES * 128) / 256, 256, 0, stream>>>(T1, row_start, cnt, inv_cnt, csr_src, b1, h);

    // layer 2: T2 = h @ [W2l | W2r]
    gemm128_kernel<<<dim3((NNODES + 127) / 128, 1), 256, 0, stream>>>(h, Wc2, T2, NNODES, 128);
    agg2_kernel<<<(NNODES * 64) / 256, 256, 0, stream>>>(T2, row_start, cnt, inv_cnt, csr_src, b2, out);
}

// Round 2
// 286.789 us; speedup vs baseline: 1.4124x; 1.4124x over previous
//
#include <hip/hip_runtime.h>

#define NNODES 40000
#define NEDGES 640000
// IN_F = 128, HID = 128, OUT_F = 64

typedef unsigned int uint32;
typedef unsigned short ushort16;

// ---------------- bf16 helpers ----------------
static __device__ __forceinline__ ushort16 f2bf(float f) {
    uint32 u = __builtin_bit_cast(uint32, f);
    uint32 r = u + 0x7fffu + ((u >> 16) & 1u);  // RNE
    return (ushort16)(r >> 16);
}
static __device__ __forceinline__ float bf_lo(uint32 u) {
    uint32 t = u << 16;
    return __builtin_bit_cast(float, t);
}
static __device__ __forceinline__ float bf_hi(uint32 u) {
    uint32 t = u & 0xffff0000u;
    return __builtin_bit_cast(float, t);
}
static __device__ __forceinline__ float bf1(ushort16 u) {
    uint32 t = ((uint32)u) << 16;
    return __builtin_bit_cast(float, t);
}

// ---------------- edge dtype detection (int64 vs int32) ----------------
__global__ void detect64_kernel(const int* __restrict__ e32, int* __restrict__ flag) {
    if (blockIdx.x == 0 && threadIdx.x == 0) {
        int any = 0;
        for (int i = 0; i < 64; ++i) any |= e32[2 * i + 1];
        *flag = (any == 0) ? 1 : 0;
    }
}

static __device__ __forceinline__ int edge_val(const void* ep, long long idx, int is64) {
    if (is64) return (int)((const long long*)ep)[idx];
    return ((const int*)ep)[idx];
}

// ---------------- CSR build ----------------
__global__ void hist_kernel(const void* __restrict__ edges, const int* __restrict__ flag,
                            int* __restrict__ cnt) {
    int e = blockIdx.x * 256 + threadIdx.x;
    if (e >= NEDGES) return;
    int is64 = *flag;
    int d = edge_val(edges, (long long)NEDGES + e, is64);
    atomicAdd(&cnt[d], 1);
}

__global__ void scan_part_kernel(const int* __restrict__ cnt, int* __restrict__ excl,
                                 int* __restrict__ bsums, int n) {
    __shared__ int s[256];
    int tid = threadIdx.x;
    int i = blockIdx.x * 256 + tid;
    int v = (i < n) ? cnt[i] : 0;
    s[tid] = v;
    __syncthreads();
    for (int off = 1; off < 256; off <<= 1) {
        int t = (tid >= off) ? s[tid - off] : 0;
        __syncthreads();
        s[tid] += t;
        __syncthreads();
    }
    if (i < n) excl[i] = s[tid] - v;
    if (tid == 255) bsums[blockIdx.x] = s[255];
}

__global__ void scan_top_kernel(const int* __restrict__ bsums, int* __restrict__ boffs, int nb) {
    __shared__ int s[256];
    int tid = threadIdx.x;
    int v = (tid < nb) ? bsums[tid] : 0;
    s[tid] = v;
    __syncthreads();
    for (int off = 1; off < 256; off <<= 1) {
        int t = (tid >= off) ? s[tid - off] : 0;
        __syncthreads();
        s[tid] += t;
        __syncthreads();
    }
    if (tid < nb) boffs[tid] = s[tid] - v;
}

__global__ void addback_kernel(const int* __restrict__ excl, const int* __restrict__ boffs,
                               const int* __restrict__ cnt, int* __restrict__ row_start,
                               int* __restrict__ cursor, float* __restrict__ inv_cnt, int n) {
    int i = blockIdx.x * 256 + threadIdx.x;
    if (i >= n) return;
    int st = excl[i] + boffs[blockIdx.x];
    row_start[i] = st;
    cursor[i] = st;
    int c = cnt[i];
    inv_cnt[i] = 1.0f / (float)(c > 0 ? c : 1);
}

__global__ void fill_kernel(const void* __restrict__ edges, const int* __restrict__ flag,
                            int* __restrict__ cursor, int* __restrict__ csr_src) {
    int e = blockIdx.x * 256 + threadIdx.x;
    if (e >= NEDGES) return;
    int is64 = *flag;
    int s = edge_val(edges, e, is64);
    int d = edge_val(edges, (long long)NEDGES + e, is64);
    int p = atomicAdd(&cursor[d], 1);
    csr_src[p] = s;
}

// ---------------- weight packing: Wc = [Wl | Wr] ----------------
__global__ void pack1_kernel(const float* __restrict__ W1l, const float* __restrict__ W1r,
                             float* __restrict__ Wc1) {
    int i = blockIdx.x * 256 + threadIdx.x;  // 128*256
    int k = i >> 8, j = i & 255;
    Wc1[i] = (j < 128) ? W1l[k * 128 + j] : W1r[k * 128 + (j - 128)];
}

__global__ void pack2_kernel(const float* __restrict__ W2l, const float* __restrict__ W2r,
                             float* __restrict__ Wc2) {
    int i = blockIdx.x * 256 + threadIdx.x;  // 128*128
    int k = i >> 7, j = i & 127;
    Wc2[i] = (j < 64) ? W2l[k * 64 + j] : W2r[k * 64 + (j - 64)];
}

// ---------------- GEMM: [A @ Wc] with split epilogue ----------------
// Left columns (< Lw) -> bf16 payload buffer bfL [nrows][Lw]
// Right columns       -> fp32 self buffer fR [nrows][CO-Lw]
__global__ __launch_bounds__(256) void gemm_kernel(const float* __restrict__ A,
                                                   const float* __restrict__ W,
                                                   int nrows, int CO, int Lw,
                                                   ushort16* __restrict__ bfL,
                                                   float* __restrict__ fR) {
    __shared__ float xs[16][132];  // [k][row] transposed A tile
    __shared__ float wt[16][132];  // [k][col] W tile
    int tid = threadIdx.x;
    int tx = tid & 15, ty = tid >> 4;
    int r0 = ty * 8, j0 = tx * 8;
    int row_base = blockIdx.x * 128;
    int col_base = blockIdx.y * 128;
    int Rw = CO - Lw;
    float acc[8][8];
#pragma unroll
    for (int i = 0; i < 8; ++i)
#pragma unroll
        for (int j = 0; j < 8; ++j) acc[i][j] = 0.f;

    for (int kc = 0; kc < 128; kc += 16) {
#pragma unroll
        for (int l = 0; l < 2; ++l) {
            int f4 = tid + l * 256;   // 0..511
            int r = f4 >> 2;          // 0..127
            int k4 = (f4 & 3) << 2;   // 0,4,8,12
            int row = row_base + r;
            float4 v = make_float4(0.f, 0.f, 0.f, 0.f);
            if (row < nrows) v = *(const float4*)&A[(size_t)row * 128 + kc + k4];
            xs[k4 + 0][r] = v.x;
            xs[k4 + 1][r] = v.y;
            xs[k4 + 2][r] = v.z;
            xs[k4 + 3][r] = v.w;
        }
#pragma unroll
        for (int l = 0; l < 2; ++l) {
            int f4 = tid + l * 256;
            int k = f4 >> 5;           // 0..15
            int j4 = (f4 & 31) << 2;   // 0..124
            *(float4*)&wt[k][j4] = *(const float4*)&W[(size_t)(kc + k) * CO + col_base + j4];
        }
        __syncthreads();
#pragma unroll
        for (int k = 0; k < 16; ++k) {
            float a[8], b[8];
            *(float4*)&a[0] = *(const float4*)&xs[k][r0];
            *(float4*)&a[4] = *(const float4*)&xs[k][r0 + 4];
            *(float4*)&b[0] = *(const float4*)&wt[k][j0];
            *(float4*)&b[4] = *(const float4*)&wt[k][j0 + 4];
#pragma unroll
            for (int i = 0; i < 8; ++i)
#pragma unroll
                for (int j = 0; j < 8; ++j) acc[i][j] = fmaf(a[i], b[j], acc[i][j]);
        }
        __syncthreads();
    }
    int jg = col_base + j0;  // 8 columns starting here, all on one side (Lw % 8 == 0)
#pragma unroll
    for (int i = 0; i < 8; ++i) {
        int row = row_base + r0 + i;
        if (row >= nrows) continue;
        if (jg < Lw) {
            uint4 pk;
            pk.x = (uint32)f2bf(acc[i][0]) | ((uint32)f2bf(acc[i][1]) << 16);
            pk.y = (uint32)f2bf(acc[i][2]) | ((uint32)f2bf(acc[i][3]) << 16);
            pk.z = (uint32)f2bf(acc[i][4]) | ((uint32)f2bf(acc[i][5]) << 16);
            pk.w = (uint32)f2bf(acc[i][6]) | ((uint32)f2bf(acc[i][7]) << 16);
            *(uint4*)&bfL[(size_t)row * Lw + jg] = pk;
        } else {
            float4 v0 = make_float4(acc[i][0], acc[i][1], acc[i][2], acc[i][3]);
            float4 v1 = make_float4(acc[i][4], acc[i][5], acc[i][6], acc[i][7]);
            *(float4*)&fR[(size_t)row * Rw + (jg - Lw)] = v0;
            *(float4*)&fR[(size_t)row * Rw + (jg - Lw) + 4] = v1;
        }
    }
}

// ---------------- layer-1 aggregation: one wave per node ----------------
// P: [N][64] uint32 (= 128 bf16 features), selfR: [N][128] fp32
__global__ __launch_bounds__(256) void agg1_kernel(const uint32* __restrict__ P,
                                                   const float* __restrict__ selfR,
                                                   const int* __restrict__ row_start,
                                                   const int* __restrict__ cnt,
                                                   const float* __restrict__ inv_cnt,
                                                   const int* __restrict__ csr_src,
                                                   const float* __restrict__ b1,
                                                   float* __restrict__ h) {
    int wave = threadIdx.x >> 6, lane = threadIdx.x & 63;
    int node = blockIdx.x * 4 + wave;
    if (node >= NNODES) return;
    int beg = row_start[node];
    int c = cnt[node];
    float s0 = 0.f, s1 = 0.f;
    for (int base = 0; base < c; base += 64) {
        int m = c - base;
        if (m > 64) m = 64;
        int idx = 0;
        if (lane < m) idx = csr_src[beg + base + lane];
        int e = 0;
        for (; e + 4 <= m; e += 4) {
            int a0 = __shfl(idx, e);
            int a1 = __shfl(idx, e + 1);
            int a2 = __shfl(idx, e + 2);
            int a3 = __shfl(idx, e + 3);
            uint32 u0 = P[(size_t)a0 * 64 + lane];
            uint32 u1 = P[(size_t)a1 * 64 + lane];
            uint32 u2 = P[(size_t)a2 * 64 + lane];
            uint32 u3 = P[(size_t)a3 * 64 + lane];
            s0 += bf_lo(u0) + bf_lo(u1) + bf_lo(u2) + bf_lo(u3);
            s1 += bf_hi(u0) + bf_hi(u1) + bf_hi(u2) + bf_hi(u3);
        }
        for (; e < m; ++e) {
            int a = __shfl(idx, e);
            uint32 u = P[(size_t)a * 64 + lane];
            s0 += bf_lo(u);
            s1 += bf_hi(u);
        }
    }
    float ic = inv_cnt[node];
    float2 sf = *(const float2*)&selfR[(size_t)node * 128 + lane * 2];
    float2 bb = *(const float2*)&b1[lane * 2];
    float v0 = fmaf(s0, ic, bb.x + sf.x);
    float v1 = fmaf(s1, ic, bb.y + sf.y);
    float2 o;
    o.x = fmaxf(v0, 0.f);
    o.y = fmaxf(v1, 0.f);
    *(float2*)&h[(size_t)node * 128 + lane * 2] = o;
}

// ---------------- layer-2 aggregation: one wave per node ----------------
// P2: [N][64] bf16, selfR2: [N][64] fp32
__global__ __launch_bounds__(256) void agg2_kernel(const ushort16* __restrict__ P2,
                                                   const float* __restrict__ selfR2,
                                                   const int* __restrict__ row_start,
                                                   const int* __restrict__ cnt,
                                                   const float* __restrict__ inv_cnt,
                                                   const int* __restrict__ csr_src,
                                                   const float* __restrict__ b2,
                                                   float* __restrict__ out) {
    int wave = threadIdx.x >> 6, lane = threadIdx.x & 63;
    int node = blockIdx.x * 4 + wave;
    if (node >= NNODES) return;
    int beg = row_start[node];
    int c = cnt[node];
    float s = 0.f;
    for (int base = 0; base < c; base += 64) {
        int m = c - base;
        if (m > 64) m = 64;
        int idx = 0;
        if (lane < m) idx = csr_src[beg + base + lane];
        int e = 0;
        for (; e + 4 <= m; e += 4) {
            int a0 = __shfl(idx, e);
            int a1 = __shfl(idx, e + 1);
            int a2 = __shfl(idx, e + 2);
            int a3 = __shfl(idx, e + 3);
            ushort16 u0 = P2[(size_t)a0 * 64 + lane];
            ushort16 u1 = P2[(size_t)a1 * 64 + lane];
            ushort16 u2 = P2[(size_t)a2 * 64 + lane];
            ushort16 u3 = P2[(size_t)a3 * 64 + lane];
            s += bf1(u0) + bf1(u1) + bf1(u2) + bf1(u3);
        }
        for (; e < m; ++e) {
            int a = __shfl(idx, e);
            s += bf1(P2[(size_t)a * 64 + lane]);
        }
    }
    float v = fmaf(s, inv_cnt[node], b2[lane] + selfR2[(size_t)node * 64 + lane]);
    out[(size_t)node * 64 + lane] = v;
}

extern "C" void kernel_launch(void* const* d_in, const int* in_sizes, int n_in,
                              void* d_out, int out_size, void* d_ws, size_t ws_size,
                              hipStream_t stream) {
    const float* x   = (const float*)d_in[0];
    const void*  ei  = d_in[1];
    const float* W1l = (const float*)d_in[2];
    const float* b1  = (const float*)d_in[3];
    const float* W1r = (const float*)d_in[4];
    const float* W2l = (const float*)d_in[5];
    const float* b2  = (const float*)d_in[6];
    const float* W2r = (const float*)d_in[7];
    float* out = (float*)d_out;

    char* p = (char*)d_ws;
    auto alloc = [&](size_t bytes) {
        char* r = p;
        p += (bytes + 255) & ~(size_t)255;
        return r;
    };
    int*      flag      = (int*)alloc(4);
    int*      cnt       = (int*)alloc(NNODES * 4);
    int*      excl      = (int*)alloc(NNODES * 4);
    int*      bsums     = (int*)alloc(256 * 4);
    int*      boffs     = (int*)alloc(256 * 4);
    int*      row_start = (int*)alloc(NNODES * 4);
    int*      cursor    = (int*)alloc(NNODES * 4);
    float*    inv_cnt   = (float*)alloc(NNODES * 4);
    int*      csr_src   = (int*)alloc((size_t)NEDGES * 4);
    float*    Wc1       = (float*)alloc(128 * 256 * 4);
    float*    Wc2       = (float*)alloc(128 * 128 * 4);
    ushort16* T1l       = (ushort16*)alloc((size_t)NNODES * 128 * 2);  // bf16 payload
    float*    T1r       = (float*)alloc((size_t)NNODES * 128 * 4);     // fp32 self
    float*    h         = (float*)alloc((size_t)NNODES * 128 * 4);
    ushort16* T2l       = (ushort16*)alloc((size_t)NNODES * 64 * 2);
    float*    T2r       = (float*)alloc((size_t)NNODES * 64 * 4);

    const int nb = (NNODES + 255) / 256;  // 157

    hipMemsetAsync(cnt, 0, NNODES * 4, stream);
    detect64_kernel<<<1, 64, 0, stream>>>((const int*)ei, flag);
    pack1_kernel<<<(128 * 256) / 256, 256, 0, stream>>>(W1l, W1r, Wc1);
    pack2_kernel<<<(128 * 128) / 256, 256, 0, stream>>>(W2l, W2r, Wc2);
    hist_kernel<<<(NEDGES + 255) / 256, 256, 0, stream>>>(ei, flag, cnt);
    scan_part_kernel<<<nb, 256, 0, stream>>>(cnt, excl, bsums, NNODES);
    scan_top_kernel<<<1, 256, 0, stream>>>(bsums, boffs, nb);
    addback_kernel<<<nb, 256, 0, stream>>>(excl, boffs, cnt, row_start, cursor, inv_cnt, NNODES);
    fill_kernel<<<(NEDGES + 255) / 256, 256, 0, stream>>>(ei, flag, cursor, csr_src);

    // layer 1: T1 = x @ [W1l | W1r]; left->bf16 payload, right->fp32 self
    gemm_kernel<<<dim3((NNODES + 127) / 128, 2), 256, 0, stream>>>(x, Wc1, NNODES, 256, 128, T1l, T1r);
    agg1_kernel<<<(NNODES + 3) / 4, 256, 0, stream>>>((const uint32*)T1l, T1r, row_start, cnt,
                                                      inv_cnt, csr_src, b1, h);

    // layer 2: T2 = h @ [W2l | W2r]
    gemm_kernel<<<dim3((NNODES + 127) / 128, 1), 256, 0, stream>>>(h, Wc2, NNODES, 128, 64, T2l, T2r);
    agg2_kernel<<<(NNODES + 3) / 4, 256, 0, stream>>>(T2l, T2r, row_start, cnt, inv_cnt, csr_src,
                                                      b2, out);
}

// Round 3
// 233.799 us; speedup vs baseline: 1.7325x; 1.2266x over previous
//
#include <hip/hip_runtime.h>

#define NNODES 40000
#define NEDGES 640000
// IN_F = 128, HID = 128, OUT_F = 64

typedef unsigned int uint32;
typedef unsigned short ushort16;
typedef short bf16x8 __attribute__((ext_vector_type(8)));
typedef float f32x4 __attribute__((ext_vector_type(4)));

// ---------------- bf16 helpers ----------------
static __device__ __forceinline__ ushort16 f2bf(float f) {
    uint32 u = __builtin_bit_cast(uint32, f);
    uint32 r = u + 0x7fffu + ((u >> 16) & 1u);  // RNE
    return (ushort16)(r >> 16);
}
static __device__ __forceinline__ float bf_lo(uint32 u) {
    uint32 t = u << 16;
    return __builtin_bit_cast(float, t);
}
static __device__ __forceinline__ float bf_hi(uint32 u) {
    uint32 t = u & 0xffff0000u;
    return __builtin_bit_cast(float, t);
}
static __device__ __forceinline__ float bf1(ushort16 u) {
    uint32 t = ((uint32)u) << 16;
    return __builtin_bit_cast(float, t);
}

// ---------------- edge dtype detection (int64 vs int32) ----------------
__global__ void detect64_kernel(const int* __restrict__ e32, int* __restrict__ flag) {
    if (blockIdx.x == 0 && threadIdx.x == 0) {
        int any = 0;
        for (int i = 0; i < 64; ++i) any |= e32[2 * i + 1];
        *flag = (any == 0) ? 1 : 0;
    }
}

static __device__ __forceinline__ int edge_val(const void* ep, long long idx, int is64) {
    if (is64) return (int)((const long long*)ep)[idx];
    return ((const int*)ep)[idx];
}

// ---------------- CSR build ----------------
__global__ void hist_kernel(const void* __restrict__ edges, const int* __restrict__ flag,
                            int* __restrict__ cnt) {
    int e = blockIdx.x * 256 + threadIdx.x;
    if (e >= NEDGES) return;
    int is64 = *flag;
    int d = edge_val(edges, (long long)NEDGES + e, is64);
    atomicAdd(&cnt[d], 1);
}

__global__ void scan_part_kernel(const int* __restrict__ cnt, int* __restrict__ excl,
                                 int* __restrict__ bsums, int n) {
    __shared__ int s[256];
    int tid = threadIdx.x;
    int i = blockIdx.x * 256 + tid;
    int v = (i < n) ? cnt[i] : 0;
    s[tid] = v;
    __syncthreads();
    for (int off = 1; off < 256; off <<= 1) {
        int t = (tid >= off) ? s[tid - off] : 0;
        __syncthreads();
        s[tid] += t;
        __syncthreads();
    }
    if (i < n) excl[i] = s[tid] - v;
    if (tid == 255) bsums[blockIdx.x] = s[255];
}

__global__ void scan_top_kernel(const int* __restrict__ bsums, int* __restrict__ boffs, int nb) {
    __shared__ int s[256];
    int tid = threadIdx.x;
    int v = (tid < nb) ? bsums[tid] : 0;
    s[tid] = v;
    __syncthreads();
    for (int off = 1; off < 256; off <<= 1) {
        int t = (tid >= off) ? s[tid - off] : 0;
        __syncthreads();
        s[tid] += t;
        __syncthreads();
    }
    if (tid < nb) boffs[tid] = s[tid] - v;
}

__global__ void addback_kernel(const int* __restrict__ excl, const int* __restrict__ boffs,
                               const int* __restrict__ cnt, int* __restrict__ row_start,
                               int* __restrict__ cursor, float* __restrict__ inv_cnt, int n) {
    int i = blockIdx.x * 256 + threadIdx.x;
    if (i >= n) return;
    int st = excl[i] + boffs[blockIdx.x];
    row_start[i] = st;
    cursor[i] = st;
    int c = cnt[i];
    inv_cnt[i] = 1.0f / (float)(c > 0 ? c : 1);
}

__global__ void fill_kernel(const void* __restrict__ edges, const int* __restrict__ flag,
                            int* __restrict__ cursor, int* __restrict__ csr_src) {
    int e = blockIdx.x * 256 + threadIdx.x;
    if (e >= NEDGES) return;
    int is64 = *flag;
    int s = edge_val(edges, e, is64);
    int d = edge_val(edges, (long long)NEDGES + e, is64);
    int p = atomicAdd(&cursor[d], 1);
    csr_src[p] = s;
}

// ---------------- x -> bf16 conversion (packed pairs) ----------------
__global__ void conv_bf16_kernel(const float* __restrict__ x, uint32* __restrict__ xbf2, int n4) {
    int i = blockIdx.x * 256 + threadIdx.x;  // one float4 -> uint2 (4 bf16)
    if (i >= n4) return;
    float4 v = ((const float4*)x)[i];
    uint2 o;
    o.x = (uint32)f2bf(v.x) | ((uint32)f2bf(v.y) << 16);
    o.y = (uint32)f2bf(v.z) | ((uint32)f2bf(v.w) << 16);
    ((uint2*)xbf2)[i] = o;
}

// ---------------- weight packing into MFMA B-fragment order ----------------
// Layout: Wfrag[by][s][nt][lane][j] (bf16), with
//   k   = s*32 + (lane>>4)*8 + j
//   col = by*128 + nt*16 + (lane&15)
// Layer 1: by in {0,1}; col<128 -> W1l[k][col], else W1r[k][col-128]
__global__ void pack1_kernel(const float* __restrict__ W1l, const float* __restrict__ W1r,
                             ushort16* __restrict__ Wfrag1) {
    int i = blockIdx.x * 256 + threadIdx.x;  // 32768
    int j = i & 7, lane = (i >> 3) & 63, nt = (i >> 9) & 7, s = (i >> 12) & 3, by = i >> 14;
    int k = s * 32 + (lane >> 4) * 8 + j;
    int col = nt * 16 + (lane & 15);
    float v = (by == 0) ? W1l[k * 128 + col] : W1r[k * 128 + col];
    Wfrag1[i] = f2bf(v);
}

// Layer 2: col = nt*16+(lane&15); col<64 -> W2l[k][col], else W2r[k][col-64]
__global__ void pack2_kernel(const float* __restrict__ W2l, const float* __restrict__ W2r,
                             ushort16* __restrict__ Wfrag2) {
    int i = blockIdx.x * 256 + threadIdx.x;  // 16384
    int j = i & 7, lane = (i >> 3) & 63, nt = (i >> 9) & 7, s = (i >> 12) & 3;
    int k = s * 32 + (lane >> 4) * 8 + j;
    int col = nt * 16 + (lane & 15);
    float v = (col < 64) ? W2l[k * 64 + col] : W2r[k * 64 + (col - 64)];
    Wfrag2[i] = f2bf(v);
}

// ---------------- MFMA GEMM: C[40000][CO] = Abf[40000][128] @ W ----------------
// block = 256 threads = 4 waves; block tile = 64 rows x 128 cols.
// Wave w: rows [blockIdx.x*64 + w*16, +16). 8 N-tiles of 16 per wave.
// Left cols (< Lw) -> bf16 payload bfL; right cols -> fp32 fR.
__global__ __launch_bounds__(256) void gemm_mfma_kernel(const ushort16* __restrict__ Abf,
                                                        const uint4* __restrict__ WfragG,
                                                        int Lw, int Rw,
                                                        ushort16* __restrict__ bfL,
                                                        float* __restrict__ fR) {
    __shared__ uint4 Bs[2048];  // 32 KB: [s][nt][lane] 16B frags
    int tid = threadIdx.x;
    // stage B fragments (contiguous, coalesced)
#pragma unroll
    for (int it = 0; it < 8; ++it) {
        int idx = tid + it * 256;
        Bs[idx] = WfragG[(size_t)blockIdx.y * 2048 + idx];
    }

    int wv = tid >> 6, lane = tid & 63;
    int quad = lane >> 4, c = lane & 15;
    int row0 = blockIdx.x * 64 + wv * 16;

    // A fragments: lane holds A[row0 + c][s*32 + quad*8 .. +8]
    const uint4* arow = (const uint4*)(Abf + (size_t)(row0 + c) * 128);
    bf16x8 af[4];
#pragma unroll
    for (int s = 0; s < 4; ++s) af[s] = __builtin_bit_cast(bf16x8, arow[s * 4 + quad]);

    __syncthreads();

    f32x4 acc[8];
#pragma unroll
    for (int nt = 0; nt < 8; ++nt) acc[nt] = (f32x4){0.f, 0.f, 0.f, 0.f};

#pragma unroll
    for (int s = 0; s < 4; ++s) {
#pragma unroll
        for (int nt = 0; nt < 8; ++nt) {
            bf16x8 bf = __builtin_bit_cast(bf16x8, Bs[(s * 8 + nt) * 64 + lane]);
            acc[nt] = __builtin_amdgcn_mfma_f32_16x16x32_bf16(af[s], bf, acc[nt], 0, 0, 0);
        }
    }

    int colbase = blockIdx.y * 128;
#pragma unroll
    for (int nt = 0; nt < 8; ++nt) {
        int gcol = colbase + nt * 16 + c;
#pragma unroll
        for (int r = 0; r < 4; ++r) {
            int row = row0 + quad * 4 + r;
            if (gcol < Lw)
                bfL[(size_t)row * Lw + gcol] = f2bf(acc[nt][r]);
            else
                fR[(size_t)row * Rw + (gcol - Lw)] = acc[nt][r];
        }
    }
}

// ---------------- layer-1 aggregation: one wave per node ----------------
// P: [N][64] uint32 (= 128 bf16), selfR: [N][128] fp32. h out: [N][64] uint32 (bf16 pairs)
__global__ __launch_bounds__(256) void agg1_kernel(const uint32* __restrict__ P,
                                                   const float* __restrict__ selfR,
                                                   const int* __restrict__ row_start,
                                                   const int* __restrict__ cnt,
                                                   const float* __restrict__ inv_cnt,
                                                   const int* __restrict__ csr_src,
                                                   const float* __restrict__ b1,
                                                   uint32* __restrict__ hbf) {
    int wave = threadIdx.x >> 6, lane = threadIdx.x & 63;
    int node = blockIdx.x * 4 + wave;
    if (node >= NNODES) return;
    int beg = row_start[node];
    int c = cnt[node];
    float s0 = 0.f, s1 = 0.f;
    for (int base = 0; base < c; base += 64) {
        int m = c - base;
        if (m > 64) m = 64;
        int idx = 0;
        if (lane < m) idx = csr_src[beg + base + lane];
        int e = 0;
        for (; e + 4 <= m; e += 4) {
            int a0 = __shfl(idx, e);
            int a1 = __shfl(idx, e + 1);
            int a2 = __shfl(idx, e + 2);
            int a3 = __shfl(idx, e + 3);
            uint32 u0 = P[(size_t)a0 * 64 + lane];
            uint32 u1 = P[(size_t)a1 * 64 + lane];
            uint32 u2 = P[(size_t)a2 * 64 + lane];
            uint32 u3 = P[(size_t)a3 * 64 + lane];
            s0 += bf_lo(u0) + bf_lo(u1) + bf_lo(u2) + bf_lo(u3);
            s1 += bf_hi(u0) + bf_hi(u1) + bf_hi(u2) + bf_hi(u3);
        }
        for (; e < m; ++e) {
            int a = __shfl(idx, e);
            uint32 u = P[(size_t)a * 64 + lane];
            s0 += bf_lo(u);
            s1 += bf_hi(u);
        }
    }
    float ic = inv_cnt[node];
    float2 sf = *(const float2*)&selfR[(size_t)node * 128 + lane * 2];
    float2 bb = *(const float2*)&b1[lane * 2];
    float v0 = fmaxf(fmaf(s0, ic, bb.x + sf.x), 0.f);
    float v1 = fmaxf(fmaf(s1, ic, bb.y + sf.y), 0.f);
    hbf[(size_t)node * 64 + lane] = (uint32)f2bf(v0) | ((uint32)f2bf(v1) << 16);
}

// ---------------- layer-2 aggregation: one wave per node ----------------
// P2: [N][64] bf16, selfR2: [N][64] fp32
__global__ __launch_bounds__(256) void agg2_kernel(const ushort16* __restrict__ P2,
                                                   const float* __restrict__ selfR2,
                                                   const int* __restrict__ row_start,
                                                   const int* __restrict__ cnt,
                                                   const float* __restrict__ inv_cnt,
                                                   const int* __restrict__ csr_src,
                                                   const float* __restrict__ b2,
                                                   float* __restrict__ out) {
    int wave = threadIdx.x >> 6, lane = threadIdx.x & 63;
    int node = blockIdx.x * 4 + wave;
    if (node >= NNODES) return;
    int beg = row_start[node];
    int c = cnt[node];
    float s = 0.f;
    for (int base = 0; base < c; base += 64) {
        int m = c - base;
        if (m > 64) m = 64;
        int idx = 0;
        if (lane < m) idx = csr_src[beg + base + lane];
        int e = 0;
        for (; e + 4 <= m; e += 4) {
            int a0 = __shfl(idx, e);
            int a1 = __shfl(idx, e + 1);
            int a2 = __shfl(idx, e + 2);
            int a3 = __shfl(idx, e + 3);
            ushort16 u0 = P2[(size_t)a0 * 64 + lane];
            ushort16 u1 = P2[(size_t)a1 * 64 + lane];
            ushort16 u2 = P2[(size_t)a2 * 64 + lane];
            ushort16 u3 = P2[(size_t)a3 * 64 + lane];
            s += bf1(u0) + bf1(u1) + bf1(u2) + bf1(u3);
        }
        for (; e < m; ++e) {
            int a = __shfl(idx, e);
            s += bf1(P2[(size_t)a * 64 + lane]);
        }
    }
    float v = fmaf(s, inv_cnt[node], b2[lane] + selfR2[(size_t)node * 64 + lane]);
    out[(size_t)node * 64 + lane] = v;
}

extern "C" void kernel_launch(void* const* d_in, const int* in_sizes, int n_in,
                              void* d_out, int out_size, void* d_ws, size_t ws_size,
                              hipStream_t stream) {
    const float* x   = (const float*)d_in[0];
    const void*  ei  = d_in[1];
    const float* W1l = (const float*)d_in[2];
    const float* b1  = (const float*)d_in[3];
    const float* W1r = (const float*)d_in[4];
    const float* W2l = (const float*)d_in[5];
    const float* b2  = (const float*)d_in[6];
    const float* W2r = (const float*)d_in[7];
    float* out = (float*)d_out;

    char* p = (char*)d_ws;
    auto alloc = [&](size_t bytes) {
        char* r = p;
        p += (bytes + 255) & ~(size_t)255;
        return r;
    };
    int*      flag      = (int*)alloc(4);
    int*      cnt       = (int*)alloc(NNODES * 4);
    int*      excl      = (int*)alloc(NNODES * 4);
    int*      bsums     = (int*)alloc(256 * 4);
    int*      boffs     = (int*)alloc(256 * 4);
    int*      row_start = (int*)alloc(NNODES * 4);
    int*      cursor    = (int*)alloc(NNODES * 4);
    float*    inv_cnt   = (float*)alloc(NNODES * 4);
    int*      csr_src   = (int*)alloc((size_t)NEDGES * 4);
    ushort16* Wfrag1    = (ushort16*)alloc(32768 * 2);   // [2][4][8][64][8] bf16
    ushort16* Wfrag2    = (ushort16*)alloc(16384 * 2);   // [4][8][64][8] bf16
    uint32*   xbf       = (uint32*)alloc((size_t)NNODES * 64 * 4);   // x in bf16
    ushort16* T1l       = (ushort16*)alloc((size_t)NNODES * 128 * 2); // bf16 payload
    float*    T1r       = (float*)alloc((size_t)NNODES * 128 * 4);    // fp32 self
    uint32*   hbf       = (uint32*)alloc((size_t)NNODES * 64 * 4);    // h in bf16
    ushort16* T2l       = (ushort16*)alloc((size_t)NNODES * 64 * 2);
    float*    T2r       = (float*)alloc((size_t)NNODES * 64 * 4);

    const int nb = (NNODES + 255) / 256;  // 157

    hipMemsetAsync(cnt, 0, NNODES * 4, stream);
    detect64_kernel<<<1, 64, 0, stream>>>((const int*)ei, flag);
    conv_bf16_kernel<<<(NNODES * 128 / 4 + 255) / 256, 256, 0, stream>>>(x, xbf, NNODES * 128 / 4);
    pack1_kernel<<<32768 / 256, 256, 0, stream>>>(W1l, W1r, Wfrag1);
    pack2_kernel<<<16384 / 256, 256, 0, stream>>>(W2l, W2r, Wfrag2);
    hist_kernel<<<(NEDGES + 255) / 256, 256, 0, stream>>>(ei, flag, cnt);
    scan_part_kernel<<<nb, 256, 0, stream>>>(cnt, excl, bsums, NNODES);
    scan_top_kernel<<<1, 256, 0, stream>>>(bsums, boffs, nb);
    addback_kernel<<<nb, 256, 0, stream>>>(excl, boffs, cnt, row_start, cursor, inv_cnt, NNODES);
    fill_kernel<<<(NEDGES + 255) / 256, 256, 0, stream>>>(ei, flag, cursor, csr_src);

    // layer 1: T1 = xbf @ [W1l | W1r]; left 128 -> bf16 payload, right 128 -> fp32 self
    gemm_mfma_kernel<<<dim3(NNODES / 64, 2), 256, 0, stream>>>(
        (const ushort16*)xbf, (const uint4*)Wfrag1, 128, 128, T1l, T1r);
    agg1_kernel<<<(NNODES + 3) / 4, 256, 0, stream>>>((const uint32*)T1l, T1r, row_start, cnt,
                                                      inv_cnt, csr_src, b1, hbf);

    // layer 2: T2 = hbf @ [W2l | W2r]; left 64 -> bf16 payload, right 64 -> fp32 self
    gemm_mfma_kernel<<<dim3(NNODES / 64, 1), 256, 0, stream>>>(
        (const ushort16*)hbf, (const uint4*)Wfrag2, 64, 64, T2l, T2r);
    agg2_kernel<<<(NNODES + 3) / 4, 256, 0, stream>>>(T2l, T2r, row_start, cnt, inv_cnt, csr_src,
                                                      b2, out);
}

// Round 4
// 222.639 us; speedup vs baseline: 1.8193x; 1.0501x over previous
//
#include <hip/hip_runtime.h>

#define NNODES 40000
#define NEDGES 640000
// IN_F = 128, HID = 128, OUT_F = 64

typedef unsigned int uint32;
typedef unsigned short ushort16;
typedef short bf16x8 __attribute__((ext_vector_type(8)));
typedef float f32x4 __attribute__((ext_vector_type(4)));

// ---------------- bf16 helpers ----------------
static __device__ __forceinline__ ushort16 f2bf(float f) {
    uint32 u = __builtin_bit_cast(uint32, f);
    uint32 r = u + 0x7fffu + ((u >> 16) & 1u);  // RNE
    return (ushort16)(r >> 16);
}
static __device__ __forceinline__ float bf_lo(uint32 u) {
    uint32 t = u << 16;
    return __builtin_bit_cast(float, t);
}
static __device__ __forceinline__ float bf_hi(uint32 u) {
    uint32 t = u & 0xffff0000u;
    return __builtin_bit_cast(float, t);
}

static __device__ __forceinline__ void acc8(float* s, uint4 u) {
    s[0] += bf_lo(u.x); s[1] += bf_hi(u.x);
    s[2] += bf_lo(u.y); s[3] += bf_hi(u.y);
    s[4] += bf_lo(u.z); s[5] += bf_hi(u.z);
    s[6] += bf_lo(u.w); s[7] += bf_hi(u.w);
}

static __device__ __forceinline__ int edge_val(const void* ep, long long idx, int is64) {
    if (is64) return (int)((const long long*)ep)[idx];
    return ((const int*)ep)[idx];
}

// ---------------- CSR build ----------------
__global__ void hist_kernel(const void* __restrict__ edges, const int* __restrict__ flag,
                            int* __restrict__ cnt) {
    int e = blockIdx.x * 256 + threadIdx.x;
    if (e >= NEDGES) return;
    int is64 = *flag;
    int d = edge_val(edges, (long long)NEDGES + e, is64);
    atomicAdd(&cnt[d], 1);
}

__global__ void scan_part_kernel(const int* __restrict__ cnt, int* __restrict__ excl,
                                 int* __restrict__ bsums, int n) {
    __shared__ int s[256];
    int tid = threadIdx.x;
    int i = blockIdx.x * 256 + tid;
    int v = (i < n) ? cnt[i] : 0;
    s[tid] = v;
    __syncthreads();
    for (int off = 1; off < 256; off <<= 1) {
        int t = (tid >= off) ? s[tid - off] : 0;
        __syncthreads();
        s[tid] += t;
        __syncthreads();
    }
    if (i < n) excl[i] = s[tid] - v;
    if (tid == 255) bsums[blockIdx.x] = s[255];
}

__global__ void scan_top_kernel(const int* __restrict__ bsums, int* __restrict__ boffs, int nb) {
    __shared__ int s[256];
    int tid = threadIdx.x;
    int v = (tid < nb) ? bsums[tid] : 0;
    s[tid] = v;
    __syncthreads();
    for (int off = 1; off < 256; off <<= 1) {
        int t = (tid >= off) ? s[tid - off] : 0;
        __syncthreads();
        s[tid] += t;
        __syncthreads();
    }
    if (tid < nb) boffs[tid] = s[tid] - v;
}

__global__ void addback_kernel(const int* __restrict__ excl, const int* __restrict__ boffs,
                               const int* __restrict__ cnt, int* __restrict__ row_start,
                               int* __restrict__ cursor, float* __restrict__ inv_cnt, int n) {
    int i = blockIdx.x * 256 + threadIdx.x;
    if (i >= n) return;
    int st = excl[i] + boffs[blockIdx.x];
    row_start[i] = st;
    cursor[i] = st;
    int c = cnt[i];
    inv_cnt[i] = 1.0f / (float)(c > 0 ? c : 1);
}

__global__ void fill_kernel(const void* __restrict__ edges, const int* __restrict__ flag,
                            int* __restrict__ cursor, int* __restrict__ csr_src) {
    int e = blockIdx.x * 256 + threadIdx.x;
    if (e >= NEDGES) return;
    int is64 = *flag;
    int s = edge_val(edges, e, is64);
    int d = edge_val(edges, (long long)NEDGES + e, is64);
    int p = atomicAdd(&cursor[d], 1);
    csr_src[p] = s;
}

// ---------------- x -> bf16 conversion (also zeroes cnt) ----------------
__global__ void conv_bf16_kernel(const float* __restrict__ x, uint32* __restrict__ xbf2, int n4,
                                 int* __restrict__ cnt) {
    int i = blockIdx.x * 256 + threadIdx.x;
    if (i < NNODES) cnt[i] = 0;  // first 157 blocks also zero the histogram
    if (i >= n4) return;
    float4 v = ((const float4*)x)[i];
    uint2 o;
    o.x = (uint32)f2bf(v.x) | ((uint32)f2bf(v.y) << 16);
    o.y = (uint32)f2bf(v.z) | ((uint32)f2bf(v.w) << 16);
    ((uint2*)xbf2)[i] = o;
}

// ---------------- weight packing into MFMA B-fragment order + edge dtype detect --------
// Wfrag[by][s][nt][lane][j] (bf16): k = s*32 + (lane>>4)*8 + j; col = by*128 + nt*16 + (lane&15)
__global__ void pack_kernel(const float* __restrict__ W1l, const float* __restrict__ W1r,
                            const float* __restrict__ W2l, const float* __restrict__ W2r,
                            ushort16* __restrict__ Wfrag1, ushort16* __restrict__ Wfrag2,
                            const int* __restrict__ e32, int* __restrict__ flag) {
    int i = blockIdx.x * 256 + threadIdx.x;  // 49152 total
    if (i == 0) {
        int any = 0;
        for (int t = 0; t < 64; ++t) any |= e32[2 * t + 1];
        *flag = (any == 0) ? 1 : 0;
    }
    if (i < 32768) {
        int j = i & 7, lane = (i >> 3) & 63, nt = (i >> 9) & 7, s = (i >> 12) & 3, by = i >> 14;
        int k = s * 32 + (lane >> 4) * 8 + j;
        int col = nt * 16 + (lane & 15);
        float v = (by == 0) ? W1l[k * 128 + col] : W1r[k * 128 + col];
        Wfrag1[i] = f2bf(v);
    } else {
        int q = i - 32768;  // 16384
        int j = q & 7, lane = (q >> 3) & 63, nt = (q >> 9) & 7, s = (q >> 12) & 3;
        int k = s * 32 + (lane >> 4) * 8 + j;
        int col = nt * 16 + (lane & 15);
        float v = (col < 64) ? W2l[k * 64 + col] : W2r[k * 64 + (col - 64)];
        Wfrag2[q] = f2bf(v);
    }
}

// ---------------- MFMA GEMM: C[40000][CO] = Abf[40000][128] @ W ----------------
// block = 256 threads = 4 waves; tile = 64 rows x 128 cols.
// Left cols (< Lw) -> bf16 bfL; right cols -> bf16 bfR (if non-null) else fp32 fR.
__global__ __launch_bounds__(256) void gemm_mfma_kernel(const ushort16* __restrict__ Abf,
                                                        const uint4* __restrict__ WfragG,
                                                        int Lw, int Rw,
                                                        ushort16* __restrict__ bfL,
                                                        ushort16* __restrict__ bfR,
                                                        float* __restrict__ fR) {
    __shared__ uint4 Bs[2048];  // 32 KB
    int tid = threadIdx.x;
#pragma unroll
    for (int it = 0; it < 8; ++it) {
        int idx = tid + it * 256;
        Bs[idx] = WfragG[(size_t)blockIdx.y * 2048 + idx];
    }

    int wv = tid >> 6, lane = tid & 63;
    int quad = lane >> 4, c = lane & 15;
    int row0 = blockIdx.x * 64 + wv * 16;

    const uint4* arow = (const uint4*)(Abf + (size_t)(row0 + c) * 128);
    bf16x8 af[4];
#pragma unroll
    for (int s = 0; s < 4; ++s) af[s] = __builtin_bit_cast(bf16x8, arow[s * 4 + quad]);

    __syncthreads();

    f32x4 acc[8];
#pragma unroll
    for (int nt = 0; nt < 8; ++nt) acc[nt] = (f32x4){0.f, 0.f, 0.f, 0.f};

#pragma unroll
    for (int s = 0; s < 4; ++s) {
#pragma unroll
        for (int nt = 0; nt < 8; ++nt) {
            bf16x8 bf = __builtin_bit_cast(bf16x8, Bs[(s * 8 + nt) * 64 + lane]);
            acc[nt] = __builtin_amdgcn_mfma_f32_16x16x32_bf16(af[s], bf, acc[nt], 0, 0, 0);
        }
    }

    int colbase = blockIdx.y * 128;
#pragma unroll
    for (int nt = 0; nt < 8; ++nt) {
        int gcol = colbase + nt * 16 + c;
#pragma unroll
        for (int r = 0; r < 4; ++r) {
            int row = row0 + quad * 4 + r;
            if (gcol < Lw) {
                bfL[(size_t)row * Lw + gcol] = f2bf(acc[nt][r]);
            } else if (bfR) {
                bfR[(size_t)row * Rw + (gcol - Lw)] = f2bf(acc[nt][r]);
            } else {
                fR[(size_t)row * Rw + (gcol - Lw)] = acc[nt][r];
            }
        }
    }
}

// ---------------- layer-1 aggregation: one wave per node, uint4 gathers ----------------
// P4: T1l [N][16] uint4 (128 bf16). S4: T1r bf16 [N][16] uint4. Out hbf4: [N][16] uint4.
__global__ __launch_bounds__(256) void agg1_kernel(const uint4* __restrict__ P4,
                                                   const uint4* __restrict__ S4,
                                                   const int* __restrict__ row_start,
                                                   const int* __restrict__ cnt,
                                                   const float* __restrict__ inv_cnt,
                                                   const int* __restrict__ csr_src,
                                                   const float* __restrict__ b1,
                                                   uint4* __restrict__ hbf4) {
    int wave = threadIdx.x >> 6, lane = threadIdx.x & 63;
    int node = blockIdx.x * 4 + wave;
    if (node >= NNODES) return;
    int beg = row_start[node];
    int c = cnt[node];
    int sub = lane >> 4;   // which edge of the 4-group
    int fl = lane & 15;    // 16B feature chunk
    float s[8];
#pragma unroll
    for (int i = 0; i < 8; ++i) s[i] = 0.f;

    for (int base = 0; base < c; base += 64) {
        int m = c - base;
        if (m > 64) m = 64;
        int idx = 0;
        if (lane < m) idx = csr_src[beg + base + lane];
        int e = 0;
        for (; e + 8 <= m; e += 8) {
            int a0 = __shfl(idx, e + sub);
            int a1 = __shfl(idx, e + 4 + sub);
            uint4 u0 = P4[(size_t)a0 * 16 + fl];
            uint4 u1 = P4[(size_t)a1 * 16 + fl];
            acc8(s, u0);
            acc8(s, u1);
        }
        for (; e < m; e += 4) {
            int ee = e + sub;
            bool pred = ee < m;
            int a = __shfl(idx, pred ? ee : 0);
            uint4 u = P4[(size_t)a * 16 + fl];
            if (pred) acc8(s, u);
        }
    }
    // reduce across the 4 edge-subsets (lanes differing in bits 4,5)
#pragma unroll
    for (int i = 0; i < 8; ++i) s[i] += __shfl_xor(s[i], 16);
#pragma unroll
    for (int i = 0; i < 8; ++i) s[i] += __shfl_xor(s[i], 32);

    if (sub == 0) {
        float ic = inv_cnt[node];
        uint4 su = S4[(size_t)node * 16 + fl];
        float4 bA = *(const float4*)&b1[fl * 8];
        float4 bB = *(const float4*)&b1[fl * 8 + 4];
        float sv[8];
        sv[0] = bf_lo(su.x); sv[1] = bf_hi(su.x);
        sv[2] = bf_lo(su.y); sv[3] = bf_hi(su.y);
        sv[4] = bf_lo(su.z); sv[5] = bf_hi(su.z);
        sv[6] = bf_lo(su.w); sv[7] = bf_hi(su.w);
        float bb[8] = {bA.x, bA.y, bA.z, bA.w, bB.x, bB.y, bB.z, bB.w};
        float v[8];
#pragma unroll
        for (int i = 0; i < 8; ++i) v[i] = fmaxf(fmaf(s[i], ic, bb[i] + sv[i]), 0.f);
        uint4 o;
        o.x = (uint32)f2bf(v[0]) | ((uint32)f2bf(v[1]) << 16);
        o.y = (uint32)f2bf(v[2]) | ((uint32)f2bf(v[3]) << 16);
        o.z = (uint32)f2bf(v[4]) | ((uint32)f2bf(v[5]) << 16);
        o.w = (uint32)f2bf(v[6]) | ((uint32)f2bf(v[7]) << 16);
        hbf4[(size_t)node * 16 + fl] = o;
    }
}

// ---------------- layer-2 aggregation: one wave per node, uint4 gathers ----------------
// P4: T2l [N][8] uint4 (64 bf16). selfR2: fp32 [N][64]. out: fp32 [N][64].
__global__ __launch_bounds__(256) void agg2_kernel(const uint4* __restrict__ P4,
                                                   const float* __restrict__ selfR2,
                                                   const int* __restrict__ row_start,
                                                   const int* __restrict__ cnt,
                                                   const float* __restrict__ inv_cnt,
                                                   const int* __restrict__ csr_src,
                                                   const float* __restrict__ b2,
                                                   float* __restrict__ out) {
    int wave = threadIdx.x >> 6, lane = threadIdx.x & 63;
    int node = blockIdx.x * 4 + wave;
    if (node >= NNODES) return;
    int beg = row_start[node];
    int c = cnt[node];
    int sub = lane >> 3;  // edge subset 0..7
    int fl = lane & 7;    // 16B feature chunk
    float s[8];
#pragma unroll
    for (int i = 0; i < 8; ++i) s[i] = 0.f;

    for (int base = 0; base < c; base += 64) {
        int m = c - base;
        if (m > 64) m = 64;
        int idx = 0;
        if (lane < m) idx = csr_src[beg + base + lane];
        int e = 0;
        for (; e + 16 <= m; e += 16) {
            int a0 = __shfl(idx, e + sub);
            int a1 = __shfl(idx, e + 8 + sub);
            uint4 u0 = P4[(size_t)a0 * 8 + fl];
            uint4 u1 = P4[(size_t)a1 * 8 + fl];
            acc8(s, u0);
            acc8(s, u1);
        }
        for (; e < m; e += 8) {
            int ee = e + sub;
            bool pred = ee < m;
            int a = __shfl(idx, pred ? ee : 0);
            uint4 u = P4[(size_t)a * 8 + fl];
            if (pred) acc8(s, u);
        }
    }
#pragma unroll
    for (int i = 0; i < 8; ++i) s[i] += __shfl_xor(s[i], 8);
#pragma unroll
    for (int i = 0; i < 8; ++i) s[i] += __shfl_xor(s[i], 16);
#pragma unroll
    for (int i = 0; i < 8; ++i) s[i] += __shfl_xor(s[i], 32);

    if (sub == 0) {
        float ic = inv_cnt[node];
        float4 sA = *(const float4*)&selfR2[(size_t)node * 64 + fl * 8];
        float4 sB = *(const float4*)&selfR2[(size_t)node * 64 + fl * 8 + 4];
        float4 bA = *(const float4*)&b2[fl * 8];
        float4 bB = *(const float4*)&b2[fl * 8 + 4];
        float sv[8] = {sA.x, sA.y, sA.z, sA.w, sB.x, sB.y, sB.z, sB.w};
        float bb[8] = {bA.x, bA.y, bA.z, bA.w, bB.x, bB.y, bB.z, bB.w};
        float v[8];
#pragma unroll
        for (int i = 0; i < 8; ++i) v[i] = fmaf(s[i], ic, bb[i] + sv[i]);
        float4 o0 = make_float4(v[0], v[1], v[2], v[3]);
        float4 o1 = make_float4(v[4], v[5], v[6], v[7]);
        *(float4*)&out[(size_t)node * 64 + fl * 8] = o0;
        *(float4*)&out[(size_t)node * 64 + fl * 8 + 4] = o1;
    }
}

extern "C" void kernel_launch(void* const* d_in, const int* in_sizes, int n_in,
                              void* d_out, int out_size, void* d_ws, size_t ws_size,
                              hipStream_t stream) {
    const float* x   = (const float*)d_in[0];
    const void*  ei  = d_in[1];
    const float* W1l = (const float*)d_in[2];
    const float* b1  = (const float*)d_in[3];
    const float* W1r = (const float*)d_in[4];
    const float* W2l = (const float*)d_in[5];
    const float* b2  = (const float*)d_in[6];
    const float* W2r = (const float*)d_in[7];
    float* out = (float*)d_out;

    char* p = (char*)d_ws;
    auto alloc = [&](size_t bytes) {
        char* r = p;
        p += (bytes + 255) & ~(size_t)255;
        return r;
    };
    int*      flag      = (int*)alloc(4);
    int*      cnt       = (int*)alloc(NNODES * 4);
    int*      excl      = (int*)alloc(NNODES * 4);
    int*      bsums     = (int*)alloc(256 * 4);
    int*      boffs     = (int*)alloc(256 * 4);
    int*      row_start = (int*)alloc(NNODES * 4);
    int*      cursor    = (int*)alloc(NNODES * 4);
    float*    inv_cnt   = (float*)alloc(NNODES * 4);
    int*      csr_src   = (int*)alloc((size_t)NEDGES * 4);
    ushort16* Wfrag1    = (ushort16*)alloc(32768 * 2);
    ushort16* Wfrag2    = (ushort16*)alloc(16384 * 2);
    uint32*   xbf       = (uint32*)alloc((size_t)NNODES * 64 * 4);    // x bf16
    ushort16* T1l       = (ushort16*)alloc((size_t)NNODES * 128 * 2); // bf16 payload
    ushort16* T1r       = (ushort16*)alloc((size_t)NNODES * 128 * 2); // bf16 self
    uint32*   hbf       = (uint32*)alloc((size_t)NNODES * 64 * 4);    // h bf16
    ushort16* T2l       = (ushort16*)alloc((size_t)NNODES * 64 * 2);
    float*    T2r       = (float*)alloc((size_t)NNODES * 64 * 4);

    const int nb = (NNODES + 255) / 256;  // 157

    conv_bf16_kernel<<<(NNODES * 128 / 4 + 255) / 256, 256, 0, stream>>>(x, xbf, NNODES * 128 / 4,
                                                                         cnt);
    pack_kernel<<<49152 / 256, 256, 0, stream>>>(W1l, W1r, W2l, W2r, Wfrag1, Wfrag2,
                                                 (const int*)ei, flag);
    hist_kernel<<<(NEDGES + 255) / 256, 256, 0, stream>>>(ei, flag, cnt);
    scan_part_kernel<<<nb, 256, 0, stream>>>(cnt, excl, bsums, NNODES);
    scan_top_kernel<<<1, 256, 0, stream>>>(bsums, boffs, nb);
    addback_kernel<<<nb, 256, 0, stream>>>(excl, boffs, cnt, row_start, cursor, inv_cnt, NNODES);
    fill_kernel<<<(NEDGES + 255) / 256, 256, 0, stream>>>(ei, flag, cursor, csr_src);

    // layer 1: T1 = xbf @ [W1l | W1r]; left 128 -> bf16 payload, right 128 -> bf16 self
    gemm_mfma_kernel<<<dim3(NNODES / 64, 2), 256, 0, stream>>>(
        (const ushort16*)xbf, (const uint4*)Wfrag1, 128, 128, T1l, T1r, (float*)nullptr);
    agg1_kernel<<<(NNODES + 3) / 4, 256, 0, stream>>>((const uint4*)T1l, (const uint4*)T1r,
                                                      row_start, cnt, inv_cnt, csr_src, b1,
                                                      (uint4*)hbf);

    // layer 2: T2 = hbf @ [W2l | W2r]; left 64 -> bf16 payload, right 64 -> fp32 self
    gemm_mfma_kernel<<<dim3(NNODES / 64, 1), 256, 0, stream>>>(
        (const ushort16*)hbf, (const uint4*)Wfrag2, 64, 64, T2l, (ushort16*)nullptr, T2r);
    agg2_kernel<<<(NNODES + 3) / 4, 256, 0, stream>>>((const uint4*)T2l, T2r, row_start, cnt,
                                                      inv_cnt, csr_src, b2, out);
}